// Round 7
// baseline (482.695 us; speedup 1.0000x reference)
//
#include <hip/hip_runtime.h>
#include <hip/hip_fp16.h>
#include <math.h>

#define N_NODES 100000
#define N_EDGES 1000000
#define IN_DIM 64
#define HID 64
#define NC 30
#define NCP 32              // padded row width for fp16 feature rows (64 B)
#define REG_C 0.01f

#define SCAN_TILE 1024
#define SCAN_NT ((N_NODES + SCAN_TILE - 1) / SCAN_TILE)   // 98
#define NTILES (N_NODES / 16)                             // 6250 exactly
#define HIST_BLOCKS ((N_EDGES + 255) / 256)               // 3907
#define GEMM_BLOCKS 1024
#define EL_BLOCKS ((N_EDGES + 255) / 256)
#define DEG_SCALE 16777216.0f                              // 2^24 fixed point

typedef _Float16 half8 __attribute__((ext_vector_type(8)));
typedef float f32x4 __attribute__((ext_vector_type(4)));

// ------- fused: u64 packed histogram (count|deg) + rank  AND  h1 = fp16(x@W1) -------
__global__ void hist_gemm(const int* __restrict__ dst, const float* __restrict__ w,
                          unsigned long long* __restrict__ packed, int* __restrict__ rank,
                          const float* __restrict__ X, const float* __restrict__ W,
                          _Float16* __restrict__ H16) {
    if (blockIdx.x < HIST_BLOCKS) {
        int e = blockIdx.x * 256 + threadIdx.x;
        if (e < N_EDGES) {
            int d = dst[e];
            unsigned long long pk = (1ULL << 40) |
                (unsigned long long)__float2uint_rn(w[e] * DEG_SCALE);
            unsigned long long old = atomicAdd(&packed[d], pk);
            rank[e] = (int)(old >> 40);
        }
        return;
    }
    // ---- GEMM part ----
    const int lane = threadIdx.x & 63;
    const int wave = threadIdx.x >> 6;
    const int q = lane >> 4;
    const int l = lane & 15;
    half8 bfrag[2][4];
#pragma unroll
    for (int kb = 0; kb < 2; ++kb)
#pragma unroll
        for (int t = 0; t < 4; ++t)
#pragma unroll
            for (int j = 0; j < 8; ++j)
                bfrag[kb][t][j] = (_Float16)W[(kb * 32 + q * 8 + j) * 64 + t * 16 + l];

    const int gb = blockIdx.x - HIST_BLOCKS;
    const int waveStride = GEMM_BLOCKS * 4;
    for (int ntile = gb * 4 + wave; ntile < NTILES; ntile += waveStride) {
        const int node0 = ntile * 16;
        const float* arow = X + (size_t)(node0 + l) * 64 + q * 8;
        half8 af0, af1;
#pragma unroll
        for (int j = 0; j < 8; ++j) {
            af0[j] = (_Float16)arow[j];
            af1[j] = (_Float16)arow[32 + j];
        }
        f32x4 acc[4];
#pragma unroll
        for (int t = 0; t < 4; ++t) acc[t] = (f32x4){0.f, 0.f, 0.f, 0.f};
#pragma unroll
        for (int t = 0; t < 4; ++t) {
            acc[t] = __builtin_amdgcn_mfma_f32_16x16x32_f16(af0, bfrag[0][t], acc[t], 0, 0, 0);
            acc[t] = __builtin_amdgcn_mfma_f32_16x16x32_f16(af1, bfrag[1][t], acc[t], 0, 0, 0);
        }
#pragma unroll
        for (int t = 0; t < 4; ++t)
#pragma unroll
            for (int r = 0; r < 4; ++r)
                H16[(size_t)(node0 + q * 4 + r) * 64 + t * 16 + l] = (_Float16)acc[t][r];
    }
}

// ------- scan phase 1, fused with dinv/invdeg computation (reads packed directly) ----
__global__ void scan_p1_dinv(const unsigned long long* __restrict__ packed,
                             int* __restrict__ blocksum, float* __restrict__ dinv,
                             float* __restrict__ invdeg) {
    __shared__ int s[256];
    int base = blockIdx.x * SCAN_TILE;
    int tid = threadIdx.x;
    int sum = 0;
#pragma unroll
    for (int j = 0; j < 4; ++j) {
        int i = base + tid * 4 + j;
        if (i < N_NODES) {
            unsigned long long p = packed[i];
            sum += (int)(p >> 40);
            float d = (float)(p & 0xFFFFFFFFFFULL) * (1.0f / DEG_SCALE) + 1.0f;
            dinv[i] = rsqrtf(d);
            invdeg[i] = 1.0f / d;
        }
    }
    s[tid] = sum;
    __syncthreads();
    for (int off = 128; off; off >>= 1) {
        if (tid < off) s[tid] += s[tid + off];
        __syncthreads();
    }
    if (tid == 0) blocksum[blockIdx.x] = s[0];
}

__global__ void scan_p2(int* __restrict__ blocksum, int* __restrict__ rowptr) {
    __shared__ int s[128];
    int tid = threadIdx.x;
    s[tid] = (tid < SCAN_NT) ? blocksum[tid] : 0;
    __syncthreads();
    if (tid == 0) {
        int run = 0;
        for (int i = 0; i < SCAN_NT; ++i) { int v = s[i]; s[i] = run; run += v; }
        rowptr[N_NODES] = N_EDGES;
    }
    __syncthreads();
    if (tid < SCAN_NT) blocksum[tid] = s[tid];
}

__global__ void scan_p3(const unsigned long long* __restrict__ packed,
                        const int* __restrict__ blocksum, int* __restrict__ rowptr) {
    __shared__ int s[256];
    int base = blockIdx.x * SCAN_TILE;
    int tid = threadIdx.x;
    int v[4];
    int sum = 0;
#pragma unroll
    for (int j = 0; j < 4; ++j) {
        int i = base + tid * 4 + j;
        v[j] = (i < N_NODES) ? (int)(packed[i] >> 40) : 0;
        sum += v[j];
    }
    s[tid] = sum;
    __syncthreads();
    for (int off = 1; off < 256; off <<= 1) {
        int t = (tid >= off) ? s[tid - off] : 0;
        __syncthreads();
        s[tid] += t;
        __syncthreads();
    }
    int run = blocksum[blockIdx.x] + (tid ? s[tid - 1] : 0);
#pragma unroll
    for (int j = 0; j < 4; ++j) {
        int i = base + tid * 4 + j;
        if (i < N_NODES) rowptr[i] = run;
        run += v[j];
    }
}

// ---------------- atomic-free placement: edata[rowptr[d]+rank[e]] = (src, norm) ----
__global__ void sort_scatter(const int* __restrict__ src, const int* __restrict__ dst,
                             const float* __restrict__ w, const float* __restrict__ dinv,
                             const int* __restrict__ rowptr, const int* __restrict__ rank,
                             int2* __restrict__ edata) {
    int e = blockIdx.x * blockDim.x + threadIdx.x;
    if (e < N_EDGES) {
        int s = src[e], d = dst[e];
        float norm = dinv[s] * w[e] * dinv[d];
        edata[rowptr[d] + rank[e]] = make_int2(s, __float_as_int(norm));
    }
}

// ------- gather-aggregate 64-dim, unroll-8 (8 outstanding misses per wave) ---------
__global__ void agg64_fused(const int* __restrict__ rowptr, const int2* __restrict__ edata,
                            const _Float16* __restrict__ H16, const float* __restrict__ invdeg,
                            const float* __restrict__ b1, _Float16* __restrict__ h2h) {
    int node = blockIdx.x * 4 + (threadIdx.x >> 6);
    int lane = threadIdx.x & 63;
    if (node >= N_NODES) return;
    int p = rowptr[node], end = rowptr[node + 1];
    float a0 = 0.f, a1 = 0.f, a2 = 0.f, a3 = 0.f;
    float a4 = 0.f, a5 = 0.f, a6 = 0.f, a7 = 0.f;
    for (; p + 7 < end; p += 8) {
        int2 e0 = edata[p],     e1 = edata[p + 1], e2 = edata[p + 2], e3 = edata[p + 3];
        int2 e4 = edata[p + 4], e5 = edata[p + 5], e6 = edata[p + 6], e7 = edata[p + 7];
        a0 += __int_as_float(e0.y) * (float)H16[(size_t)e0.x * 64 + lane];
        a1 += __int_as_float(e1.y) * (float)H16[(size_t)e1.x * 64 + lane];
        a2 += __int_as_float(e2.y) * (float)H16[(size_t)e2.x * 64 + lane];
        a3 += __int_as_float(e3.y) * (float)H16[(size_t)e3.x * 64 + lane];
        a4 += __int_as_float(e4.y) * (float)H16[(size_t)e4.x * 64 + lane];
        a5 += __int_as_float(e5.y) * (float)H16[(size_t)e5.x * 64 + lane];
        a6 += __int_as_float(e6.y) * (float)H16[(size_t)e6.x * 64 + lane];
        a7 += __int_as_float(e7.y) * (float)H16[(size_t)e7.x * 64 + lane];
    }
    for (; p + 1 < end; p += 2) {
        int2 e0 = edata[p], e1 = edata[p + 1];
        a0 += __int_as_float(e0.y) * (float)H16[(size_t)e0.x * 64 + lane];
        a1 += __int_as_float(e1.y) * (float)H16[(size_t)e1.x * 64 + lane];
    }
    if (p < end) {
        int2 e0 = edata[p];
        a0 += __int_as_float(e0.y) * (float)H16[(size_t)e0.x * 64 + lane];
    }
    float v = ((a0 + a1) + (a2 + a3)) + ((a4 + a5) + (a6 + a7)) +
              (float)H16[(size_t)node * 64 + lane] * invdeg[node] + b1[lane];
    h2h[(size_t)node * 64 + lane] = (_Float16)fmaxf(v, 0.f);
}

// ---------------- hh16 = fp16(h2 @ W2), padded 32-wide rows ----------------
__global__ void linear30(const _Float16* __restrict__ H, const float* __restrict__ W2,
                         __half* __restrict__ HH16) {
    __shared__ float sW[64 * NC];
    __shared__ float sH[8 * 64];
    for (int i = threadIdx.x; i < 64 * NC; i += blockDim.x) sW[i] = W2[i];
    int node0 = blockIdx.x * 8;
    for (int i = threadIdx.x; i < 8 * 64; i += blockDim.x) {
        int n = node0 + (i >> 6);
        sH[i] = (n < N_NODES) ? (float)H[(size_t)n * 64 + (i & 63)] : 0.f;
    }
    __syncthreads();
    int ln = threadIdx.x >> 5;
    int c = threadIdx.x & 31;
    int node = node0 + ln;
    if (node < N_NODES) {
        float acc = 0.f;
        if (c < NC) {
#pragma unroll
            for (int k = 0; k < 64; ++k) acc += sH[ln * 64 + k] * sW[k * NC + c];
        }
        HH16[(size_t)node * NCP + c] = __float2half(acc);
    }
}

// ------- gather-aggregate 30-dim + softmax, unroll-4 (4 outstanding per half) ------
__global__ void agg30_softmax_colsum(const int* __restrict__ rowptr, const int2* __restrict__ edata,
                                     const __half* __restrict__ HH16,
                                     const float* __restrict__ invdeg,
                                     const float* __restrict__ b2, float* __restrict__ FX,
                                     __half* __restrict__ FX16, float* __restrict__ colsum) {
    const int lane = threadIdx.x & 63;
    const int waveInBlock = threadIdx.x >> 6;
    const int half = lane >> 5;
    const int c = lane & 31;
    const bool activeC = (c < NC);
    const int wavesTotal = gridDim.x * (blockDim.x >> 6);
    const int w0 = blockIdx.x * (blockDim.x >> 6) + waveInBlock;

    const float bb = activeC ? b2[c] : 0.f;
    float lacc = 0.f;

    for (int pair = w0; pair < N_NODES / 2; pair += wavesTotal) {
        const int node = pair * 2 + half;
        int p = rowptr[node], end = rowptr[node + 1];
        float acc0 = 0.f, acc1 = 0.f, acc2 = 0.f, acc3 = 0.f;
        for (; p + 3 < end; p += 4) {
            int2 e0 = edata[p],     e1 = edata[p + 1];
            int2 e2 = edata[p + 2], e3 = edata[p + 3];
            acc0 += __int_as_float(e0.y) * __half2float(HH16[(size_t)e0.x * NCP + c]);
            acc1 += __int_as_float(e1.y) * __half2float(HH16[(size_t)e1.x * NCP + c]);
            acc2 += __int_as_float(e2.y) * __half2float(HH16[(size_t)e2.x * NCP + c]);
            acc3 += __int_as_float(e3.y) * __half2float(HH16[(size_t)e3.x * NCP + c]);
        }
        for (; p < end; ++p) {
            int2 e0 = edata[p];
            acc0 += __int_as_float(e0.y) * __half2float(HH16[(size_t)e0.x * NCP + c]);
        }
        float selfv = __half2float(HH16[(size_t)node * NCP + c]);
        float x = activeC ? ((acc0 + acc1) + (acc2 + acc3) + selfv * invdeg[node] + bb)
                          : -INFINITY;
        float mx = x;
        for (int off = 16; off; off >>= 1) mx = fmaxf(mx, __shfl_xor(mx, off));
        float e = activeC ? expf(x - mx) : 0.f;
        float s = e;
        for (int off = 16; off; off >>= 1) s += __shfl_xor(s, off);
        float fx = e / s;
        if (activeC) {
            FX[(size_t)node * NC + c] = fx;
            FX16[(size_t)node * NCP + c] = __float2half(fx);
            lacc += log1pf(-fx * fx);
        } else {
            FX16[(size_t)node * NCP + c] = __float2half(0.f);
        }
    }
    lacc += __shfl_xor(lacc, 32);
    __shared__ float part[4][NC];
    if (half == 0 && activeC) part[waveInBlock][c] = lacc;
    __syncthreads();
    if (threadIdx.x < NC) {
        float v = part[0][threadIdx.x] + part[1][threadIdx.x] +
                  part[2][threadIdx.x] + part[3][threadIdx.x];
        atomicAdd(&colsum[threadIdx.x], v);
    }
}

// ------- edge loss (one edge/lane, 8 outstanding row loads) + fused finalize -------
__global__ void edge_loss_final(const int* __restrict__ src, const int* __restrict__ dst,
                                const float* __restrict__ w, const uint4* __restrict__ FX16u,
                                float* __restrict__ mse, int* __restrict__ done,
                                const float* __restrict__ colsum, float* __restrict__ out_loss) {
    int e = blockIdx.x * blockDim.x + threadIdx.x;
    float v = 0.f;
    if (e < N_EDGES) {
        int s = src[e], d = dst[e];
        const uint4* rs = FX16u + (size_t)s * 4;
        const uint4* rd = FX16u + (size_t)d * 4;
        __half2 acc[4];
#pragma unroll
        for (int i = 0; i < 4; ++i) acc[i] = __half2half2(__float2half(0.f));
#pragma unroll
        for (int i = 0; i < 4; ++i) {
            uint4 a = rs[i];
            uint4 b = rd[i];
            acc[0] = __hfma2(*(const __half2*)&a.x, *(const __half2*)&b.x, acc[0]);
            acc[1] = __hfma2(*(const __half2*)&a.y, *(const __half2*)&b.y, acc[1]);
            acc[2] = __hfma2(*(const __half2*)&a.z, *(const __half2*)&b.z, acc[2]);
            acc[3] = __hfma2(*(const __half2*)&a.w, *(const __half2*)&b.w, acc[3]);
        }
        float ff = 0.f;
#pragma unroll
        for (int i = 0; i < 4; ++i)
            ff += __low2float(acc[i]) + __high2float(acc[i]);
        float diff = ff - w[e];
        v = diff * diff;
    }
    for (int off = 32; off > 0; off >>= 1) v += __shfl_down(v, off);
    __shared__ float ps[4];
    int lane = threadIdx.x & 63, wv = threadIdx.x >> 6;
    if (lane == 0) ps[wv] = v;
    __syncthreads();
    if (threadIdx.x == 0) {
        atomicAdd(mse, ps[0] + ps[1] + ps[2] + ps[3]);
        __threadfence();
        int prev = atomicAdd(done, 1);
        if (prev == (int)gridDim.x - 1) {
            // last block: all mse contributions visible (threadfence before each inc)
            float m = atomicAdd(mse, 0.0f);   // coherent read
            float preg = 0.f;
            for (int cc = 0; cc < NC; ++cc)
                preg -= logf(1.0001f - expf(colsum[cc]));
            out_loss[0] = m / (float)N_EDGES + REG_C * preg;
        }
    }
}

extern "C" void kernel_launch(void* const* d_in, const int* in_sizes, int n_in,
                              void* d_out, int out_size, void* d_ws, size_t ws_size,
                              hipStream_t stream) {
    const float* x  = (const float*)d_in[0];
    const int*   ei = (const int*)d_in[1];
    const float* ea = (const float*)d_in[2];
    const float* W1 = (const float*)d_in[3];
    const float* b1 = (const float*)d_in[4];
    const float* W2 = (const float*)d_in[5];
    const float* b2 = (const float*)d_in[6];
    const int* srcI = ei;
    const int* dstI = ei + N_EDGES;

    float* FX   = (float*)d_out;
    float* loss = FX + (size_t)N_NODES * NC;

    // workspace layout -- explicit float-element offsets; 8B/16B alignment kept
    float* ws = (float*)d_ws;
    float*    dinv   = ws;                            // N
    float*    invdeg = ws + 100000;                   // N
    _Float16* h1h    = (_Float16*)(ws + 200000);      // 64N halves = 3.2M floats
    _Float16* h2h    = (_Float16*)(ws + 3400000);     // 64N halves
    __half*   hh16   = (__half*)(ws + 6600000);       // 32N halves = 1.6M floats
    __half*   fx16   = (__half*)(ws + 8200000);       // 32N halves
    float*    colsum = ws + 9800000;                  // 32
    float*    mse    = ws + 9800032;                  // 1
    int*      done   = (int*)(ws + 9800033);          // 1
    int*      rowptr = (int*)(ws + 9800064);          // N+1
    int*      bsum   = (int*)(ws + 9900066);          // 130
    unsigned long long* packed = (unsigned long long*)(ws + 9900200);  // N u64
    int*      rank   = (int*)(ws + 10100200);         // E
    int2*     edata  = (int2*)(ws + 11100200);        // E int2

    hipMemsetAsync(packed, 0, N_NODES * sizeof(unsigned long long), stream);
    hipMemsetAsync(colsum, 0, 34 * sizeof(float), stream);  // colsum + mse + done

    hist_gemm<<<HIST_BLOCKS + GEMM_BLOCKS, 256, 0, stream>>>(dstI, ea, packed, rank,
                                                             x, W1, h1h);
    scan_p1_dinv<<<SCAN_NT, 256, 0, stream>>>(packed, bsum, dinv, invdeg);
    scan_p2<<<1, 128, 0, stream>>>(bsum, rowptr);
    scan_p3<<<SCAN_NT, 256, 0, stream>>>(packed, bsum, rowptr);
    sort_scatter<<<(N_EDGES + 255) / 256, 256, 0, stream>>>(srcI, dstI, ea, dinv,
                                                            rowptr, rank, edata);
    agg64_fused<<<(N_NODES + 3) / 4, 256, 0, stream>>>(rowptr, edata, h1h, invdeg, b1, h2h);
    linear30<<<(N_NODES + 7) / 8, 256, 0, stream>>>(h2h, W2, hh16);
    agg30_softmax_colsum<<<4096, 256, 0, stream>>>(rowptr, edata, hh16, invdeg, b2,
                                                   FX, fx16, colsum);
    edge_loss_final<<<EL_BLOCKS, 256, 0, stream>>>(srcI, dstI, ea, (const uint4*)fx16,
                                                   mse, done, colsum, loss);
}

// Round 8
// 383.032 us; speedup vs baseline: 1.2602x; 1.2602x over previous
//
#include <hip/hip_runtime.h>
#include <hip/hip_fp16.h>
#include <math.h>

#define N_NODES 100000
#define N_EDGES 1000000
#define IN_DIM 64
#define HID 64
#define NC 30
#define NCP 32              // padded row width for fp16 feature rows (64 B)
#define REG_C 0.01f

#define SCAN_TILE 1024
#define SCAN_NT ((N_NODES + SCAN_TILE - 1) / SCAN_TILE)   // 98
#define NTILES (N_NODES / 16)                             // 6250 exactly
#define HIST_BLOCKS ((N_EDGES + 255) / 256)               // 3907
#define GEMM_BLOCKS 1024
#define DEG_SCALE 16777216.0f                              // 2^24 fixed point

typedef _Float16 half8 __attribute__((ext_vector_type(8)));
typedef float f32x4 __attribute__((ext_vector_type(4)));

// ------- fused: u64 packed histogram (count|deg) + rank  AND  h1 = fp16(x@W1) -------
__global__ void hist_gemm(const int* __restrict__ dst, const float* __restrict__ w,
                          unsigned long long* __restrict__ packed, int* __restrict__ rank,
                          const float* __restrict__ X, const float* __restrict__ W,
                          _Float16* __restrict__ H16) {
    if (blockIdx.x < HIST_BLOCKS) {
        int e = blockIdx.x * 256 + threadIdx.x;
        if (e < N_EDGES) {
            int d = dst[e];
            unsigned long long pk = (1ULL << 40) |
                (unsigned long long)__float2uint_rn(w[e] * DEG_SCALE);
            unsigned long long old = atomicAdd(&packed[d], pk);
            rank[e] = (int)(old >> 40);
        }
        return;
    }
    // ---- GEMM part ----
    const int lane = threadIdx.x & 63;
    const int wave = threadIdx.x >> 6;
    const int q = lane >> 4;
    const int l = lane & 15;
    half8 bfrag[2][4];
#pragma unroll
    for (int kb = 0; kb < 2; ++kb)
#pragma unroll
        for (int t = 0; t < 4; ++t)
#pragma unroll
            for (int j = 0; j < 8; ++j)
                bfrag[kb][t][j] = (_Float16)W[(kb * 32 + q * 8 + j) * 64 + t * 16 + l];

    const int gb = blockIdx.x - HIST_BLOCKS;
    const int waveStride = GEMM_BLOCKS * 4;
    for (int ntile = gb * 4 + wave; ntile < NTILES; ntile += waveStride) {
        const int node0 = ntile * 16;
        const float* arow = X + (size_t)(node0 + l) * 64 + q * 8;
        half8 af0, af1;
#pragma unroll
        for (int j = 0; j < 8; ++j) {
            af0[j] = (_Float16)arow[j];
            af1[j] = (_Float16)arow[32 + j];
        }
        f32x4 acc[4];
#pragma unroll
        for (int t = 0; t < 4; ++t) acc[t] = (f32x4){0.f, 0.f, 0.f, 0.f};
#pragma unroll
        for (int t = 0; t < 4; ++t) {
            acc[t] = __builtin_amdgcn_mfma_f32_16x16x32_f16(af0, bfrag[0][t], acc[t], 0, 0, 0);
            acc[t] = __builtin_amdgcn_mfma_f32_16x16x32_f16(af1, bfrag[1][t], acc[t], 0, 0, 0);
        }
#pragma unroll
        for (int t = 0; t < 4; ++t)
#pragma unroll
            for (int r = 0; r < 4; ++r)
                H16[(size_t)(node0 + q * 4 + r) * 64 + t * 16 + l] = (_Float16)acc[t][r];
    }
}

// ------- scan phase 1, fused with dinv/invdeg computation ----------------
__global__ void scan_p1_dinv(const unsigned long long* __restrict__ packed,
                             int* __restrict__ blocksum, float* __restrict__ dinv,
                             float* __restrict__ invdeg) {
    __shared__ int s[256];
    int base = blockIdx.x * SCAN_TILE;
    int tid = threadIdx.x;
    int sum = 0;
#pragma unroll
    for (int j = 0; j < 4; ++j) {
        int i = base + tid * 4 + j;
        if (i < N_NODES) {
            unsigned long long p = packed[i];
            sum += (int)(p >> 40);
            float d = (float)(p & 0xFFFFFFFFFFULL) * (1.0f / DEG_SCALE) + 1.0f;
            dinv[i] = rsqrtf(d);
            invdeg[i] = 1.0f / d;
        }
    }
    s[tid] = sum;
    __syncthreads();
    for (int off = 128; off; off >>= 1) {
        if (tid < off) s[tid] += s[tid + off];
        __syncthreads();
    }
    if (tid == 0) blocksum[blockIdx.x] = s[0];
}

__global__ void scan_p2(int* __restrict__ blocksum, int* __restrict__ rowptr) {
    __shared__ int s[128];
    int tid = threadIdx.x;
    s[tid] = (tid < SCAN_NT) ? blocksum[tid] : 0;
    __syncthreads();
    if (tid == 0) {
        int run = 0;
        for (int i = 0; i < SCAN_NT; ++i) { int v = s[i]; s[i] = run; run += v; }
        rowptr[N_NODES] = N_EDGES;
    }
    __syncthreads();
    if (tid < SCAN_NT) blocksum[tid] = s[tid];
}

__global__ void scan_p3(const unsigned long long* __restrict__ packed,
                        const int* __restrict__ blocksum, int* __restrict__ rowptr) {
    __shared__ int s[256];
    int base = blockIdx.x * SCAN_TILE;
    int tid = threadIdx.x;
    int v[4];
    int sum = 0;
#pragma unroll
    for (int j = 0; j < 4; ++j) {
        int i = base + tid * 4 + j;
        v[j] = (i < N_NODES) ? (int)(packed[i] >> 40) : 0;
        sum += v[j];
    }
    s[tid] = sum;
    __syncthreads();
    for (int off = 1; off < 256; off <<= 1) {
        int t = (tid >= off) ? s[tid - off] : 0;
        __syncthreads();
        s[tid] += t;
        __syncthreads();
    }
    int run = blocksum[blockIdx.x] + (tid ? s[tid - 1] : 0);
#pragma unroll
    for (int j = 0; j < 4; ++j) {
        int i = base + tid * 4 + j;
        if (i < N_NODES) rowptr[i] = run;
        run += v[j];
    }
}

// ------- atomic-free placement: edata[rowptr[d]+rank[e]] = (src, norm, w, dst) -----
__global__ void sort_scatter(const int* __restrict__ src, const int* __restrict__ dst,
                             const float* __restrict__ w, const float* __restrict__ dinv,
                             const int* __restrict__ rowptr, const int* __restrict__ rank,
                             int4* __restrict__ edata) {
    int e = blockIdx.x * blockDim.x + threadIdx.x;
    if (e < N_EDGES) {
        int s = src[e], d = dst[e];
        float we = w[e];
        float norm = dinv[s] * we * dinv[d];
        edata[rowptr[d] + rank[e]] =
            make_int4(s, __float_as_int(norm), __float_as_int(we), d);
    }
}

// ------- gather-aggregate 64-dim, unroll-8 (8 outstanding misses per wave) ---------
__global__ void agg64_fused(const int* __restrict__ rowptr, const int4* __restrict__ edata,
                            const _Float16* __restrict__ H16, const float* __restrict__ invdeg,
                            const float* __restrict__ b1, _Float16* __restrict__ h2h) {
    int node = blockIdx.x * 4 + (threadIdx.x >> 6);
    int lane = threadIdx.x & 63;
    if (node >= N_NODES) return;
    int p = rowptr[node], end = rowptr[node + 1];
    float a0 = 0.f, a1 = 0.f, a2 = 0.f, a3 = 0.f;
    float a4 = 0.f, a5 = 0.f, a6 = 0.f, a7 = 0.f;
    for (; p + 7 < end; p += 8) {
        int4 e0 = edata[p],     e1 = edata[p + 1], e2 = edata[p + 2], e3 = edata[p + 3];
        int4 e4 = edata[p + 4], e5 = edata[p + 5], e6 = edata[p + 6], e7 = edata[p + 7];
        a0 += __int_as_float(e0.y) * (float)H16[(size_t)e0.x * 64 + lane];
        a1 += __int_as_float(e1.y) * (float)H16[(size_t)e1.x * 64 + lane];
        a2 += __int_as_float(e2.y) * (float)H16[(size_t)e2.x * 64 + lane];
        a3 += __int_as_float(e3.y) * (float)H16[(size_t)e3.x * 64 + lane];
        a4 += __int_as_float(e4.y) * (float)H16[(size_t)e4.x * 64 + lane];
        a5 += __int_as_float(e5.y) * (float)H16[(size_t)e5.x * 64 + lane];
        a6 += __int_as_float(e6.y) * (float)H16[(size_t)e6.x * 64 + lane];
        a7 += __int_as_float(e7.y) * (float)H16[(size_t)e7.x * 64 + lane];
    }
    for (; p + 1 < end; p += 2) {
        int4 e0 = edata[p], e1 = edata[p + 1];
        a0 += __int_as_float(e0.y) * (float)H16[(size_t)e0.x * 64 + lane];
        a1 += __int_as_float(e1.y) * (float)H16[(size_t)e1.x * 64 + lane];
    }
    if (p < end) {
        int4 e0 = edata[p];
        a0 += __int_as_float(e0.y) * (float)H16[(size_t)e0.x * 64 + lane];
    }
    float v = ((a0 + a1) + (a2 + a3)) + ((a4 + a5) + (a6 + a7)) +
              (float)H16[(size_t)node * 64 + lane] * invdeg[node] + b1[lane];
    h2h[(size_t)node * 64 + lane] = (_Float16)fmaxf(v, 0.f);
}

// ---------------- hh16 = fp16(h2 @ W2), padded 32-wide rows ----------------
__global__ void linear30(const _Float16* __restrict__ H, const float* __restrict__ W2,
                         __half* __restrict__ HH16) {
    __shared__ float sW[64 * NC];
    __shared__ float sH[8 * 64];
    for (int i = threadIdx.x; i < 64 * NC; i += blockDim.x) sW[i] = W2[i];
    int node0 = blockIdx.x * 8;
    for (int i = threadIdx.x; i < 8 * 64; i += blockDim.x) {
        int n = node0 + (i >> 6);
        sH[i] = (n < N_NODES) ? (float)H[(size_t)n * 64 + (i & 63)] : 0.f;
    }
    __syncthreads();
    int ln = threadIdx.x >> 5;
    int c = threadIdx.x & 31;
    int node = node0 + ln;
    if (node < N_NODES) {
        float acc = 0.f;
        if (c < NC) {
#pragma unroll
            for (int k = 0; k < 64; ++k) acc += sH[ln * 64 + k] * sW[k * NC + c];
        }
        HH16[(size_t)node * NCP + c] = __float2half(acc);
    }
}

// ------- gather-aggregate 30-dim + softmax, unroll-4 -------------------------------
__global__ void agg30_softmax_colsum(const int* __restrict__ rowptr, const int4* __restrict__ edata,
                                     const __half* __restrict__ HH16,
                                     const float* __restrict__ invdeg,
                                     const float* __restrict__ b2, float* __restrict__ FX,
                                     __half* __restrict__ FX16, float* __restrict__ colsum) {
    const int lane = threadIdx.x & 63;
    const int waveInBlock = threadIdx.x >> 6;
    const int half = lane >> 5;
    const int c = lane & 31;
    const bool activeC = (c < NC);
    const int wavesTotal = gridDim.x * (blockDim.x >> 6);
    const int w0 = blockIdx.x * (blockDim.x >> 6) + waveInBlock;

    const float bb = activeC ? b2[c] : 0.f;
    float lacc = 0.f;

    for (int pair = w0; pair < N_NODES / 2; pair += wavesTotal) {
        const int node = pair * 2 + half;
        int p = rowptr[node], end = rowptr[node + 1];
        float acc0 = 0.f, acc1 = 0.f, acc2 = 0.f, acc3 = 0.f;
        for (; p + 3 < end; p += 4) {
            int4 e0 = edata[p],     e1 = edata[p + 1];
            int4 e2 = edata[p + 2], e3 = edata[p + 3];
            acc0 += __int_as_float(e0.y) * __half2float(HH16[(size_t)e0.x * NCP + c]);
            acc1 += __int_as_float(e1.y) * __half2float(HH16[(size_t)e1.x * NCP + c]);
            acc2 += __int_as_float(e2.y) * __half2float(HH16[(size_t)e2.x * NCP + c]);
            acc3 += __int_as_float(e3.y) * __half2float(HH16[(size_t)e3.x * NCP + c]);
        }
        for (; p < end; ++p) {
            int4 e0 = edata[p];
            acc0 += __int_as_float(e0.y) * __half2float(HH16[(size_t)e0.x * NCP + c]);
        }
        float selfv = __half2float(HH16[(size_t)node * NCP + c]);
        float x = activeC ? ((acc0 + acc1) + (acc2 + acc3) + selfv * invdeg[node] + bb)
                          : -INFINITY;
        float mx = x;
        for (int off = 16; off; off >>= 1) mx = fmaxf(mx, __shfl_xor(mx, off));
        float e = activeC ? expf(x - mx) : 0.f;
        float s = e;
        for (int off = 16; off; off >>= 1) s += __shfl_xor(s, off);
        float fx = e / s;
        if (activeC) {
            FX[(size_t)node * NC + c] = fx;
            FX16[(size_t)node * NCP + c] = __float2half(fx);
            lacc += log1pf(-fx * fx);
        } else {
            FX16[(size_t)node * NCP + c] = __float2half(0.f);
        }
    }
    lacc += __shfl_xor(lacc, 32);
    __shared__ float part[4][NC];
    if (half == 0 && activeC) part[waveInBlock][c] = lacc;
    __syncthreads();
    if (threadIdx.x < NC) {
        float v = part[0][threadIdx.x] + part[1][threadIdx.x] +
                  part[2][threadIdx.x] + part[3][threadIdx.x];
        atomicAdd(&colsum[threadIdx.x], v);
    }
}

// ------- edge loss over dst-sorted edges: dst rows hit cache (runs of same dst) ----
// One edge per lane; full 32-half dot in-lane (no shuffles); only FX16[src] is a
// true random gather. NO device-scope fences here (R7 lesson: __threadfence per
// block doubled this kernel's time via L2-scope cache ops).
__global__ void edge_loss_sorted(const int4* __restrict__ edata, const uint4* __restrict__ FX16u,
                                 float* __restrict__ mse) {
    int e = blockIdx.x * blockDim.x + threadIdx.x;
    float v = 0.f;
    if (e < N_EDGES) {
        int4 ed = edata[e];
        const uint4* rs = FX16u + (size_t)ed.x * 4;
        const uint4* rd = FX16u + (size_t)ed.w * 4;
        __half2 acc[4];
#pragma unroll
        for (int i = 0; i < 4; ++i) acc[i] = __half2half2(__float2half(0.f));
#pragma unroll
        for (int i = 0; i < 4; ++i) {
            uint4 a = rs[i];
            uint4 b = rd[i];
            acc[0] = __hfma2(*(const __half2*)&a.x, *(const __half2*)&b.x, acc[0]);
            acc[1] = __hfma2(*(const __half2*)&a.y, *(const __half2*)&b.y, acc[1]);
            acc[2] = __hfma2(*(const __half2*)&a.z, *(const __half2*)&b.z, acc[2]);
            acc[3] = __hfma2(*(const __half2*)&a.w, *(const __half2*)&b.w, acc[3]);
        }
        float ff = 0.f;
#pragma unroll
        for (int i = 0; i < 4; ++i)
            ff += __low2float(acc[i]) + __high2float(acc[i]);
        float diff = ff - __int_as_float(ed.z);
        v = diff * diff;
    }
    for (int off = 32; off > 0; off >>= 1) v += __shfl_down(v, off);
    __shared__ float ps[4];
    int lane = threadIdx.x & 63, wv = threadIdx.x >> 6;
    if (lane == 0) ps[wv] = v;
    __syncthreads();
    if (threadIdx.x == 0) atomicAdd(mse, ps[0] + ps[1] + ps[2] + ps[3]);
}

// ---------------- finalize: preg + loss ----------------
__global__ void finalize(const float* __restrict__ colsum, const float* __restrict__ mse,
                         float* __restrict__ out_loss) {
    int c = threadIdx.x;
    float term = 0.f;
    if (c < NC) term = logf(1.0001f - expf(colsum[c]));
    for (int off = 32; off > 0; off >>= 1) term += __shfl_down(term, off);
    if (threadIdx.x == 0) {
        float preg = -term;
        out_loss[0] = mse[0] / (float)N_EDGES + REG_C * preg;
    }
}

extern "C" void kernel_launch(void* const* d_in, const int* in_sizes, int n_in,
                              void* d_out, int out_size, void* d_ws, size_t ws_size,
                              hipStream_t stream) {
    const float* x  = (const float*)d_in[0];
    const int*   ei = (const int*)d_in[1];
    const float* ea = (const float*)d_in[2];
    const float* W1 = (const float*)d_in[3];
    const float* b1 = (const float*)d_in[4];
    const float* W2 = (const float*)d_in[5];
    const float* b2 = (const float*)d_in[6];
    const int* srcI = ei;
    const int* dstI = ei + N_EDGES;

    float* FX   = (float*)d_out;
    float* loss = FX + (size_t)N_NODES * NC;

    // workspace layout -- explicit float-element offsets; edata offset /4 for int4
    float* ws = (float*)d_ws;
    float*    dinv   = ws;                            // N
    float*    invdeg = ws + 100000;                   // N
    _Float16* h1h    = (_Float16*)(ws + 200000);      // 64N halves = 3.2M floats
    _Float16* h2h    = (_Float16*)(ws + 3400000);     // 64N halves
    __half*   hh16   = (__half*)(ws + 6600000);       // 32N halves = 1.6M floats
    __half*   fx16   = (__half*)(ws + 8200000);       // 32N halves
    float*    colsum = ws + 9800000;                  // 32
    float*    mse    = ws + 9800032;                  // 1
    int*      rowptr = (int*)(ws + 9800064);          // N+1
    int*      bsum   = (int*)(ws + 9900066);          // 130
    unsigned long long* packed = (unsigned long long*)(ws + 9900200);  // N u64
    int*      rank   = (int*)(ws + 10100200);         // E
    int4*     edata  = (int4*)(ws + 11100200);        // E int4 = 4M floats (16B-aligned)

    hipMemsetAsync(packed, 0, N_NODES * sizeof(unsigned long long), stream);
    hipMemsetAsync(colsum, 0, 34 * sizeof(float), stream);

    hist_gemm<<<HIST_BLOCKS + GEMM_BLOCKS, 256, 0, stream>>>(dstI, ea, packed, rank,
                                                             x, W1, h1h);
    scan_p1_dinv<<<SCAN_NT, 256, 0, stream>>>(packed, bsum, dinv, invdeg);
    scan_p2<<<1, 128, 0, stream>>>(bsum, rowptr);
    scan_p3<<<SCAN_NT, 256, 0, stream>>>(packed, bsum, rowptr);
    sort_scatter<<<(N_EDGES + 255) / 256, 256, 0, stream>>>(srcI, dstI, ea, dinv,
                                                            rowptr, rank, edata);
    agg64_fused<<<(N_NODES + 3) / 4, 256, 0, stream>>>(rowptr, edata, h1h, invdeg, b1, h2h);
    linear30<<<(N_NODES + 7) / 8, 256, 0, stream>>>(h2h, W2, hh16);
    agg30_softmax_colsum<<<4096, 256, 0, stream>>>(rowptr, edata, hh16, invdeg, b2,
                                                   FX, fx16, colsum);
    edge_loss_sorted<<<(N_EDGES + 255) / 256, 256, 0, stream>>>(edata, (const uint4*)fx16, mse);
    finalize<<<1, 64, 0, stream>>>(colsum, mse, loss);
}